// Round 15
// baseline (285.190 us; speedup 1.0000x reference)
//
#include <hip/hip_runtime.h>
#include <hip/hip_bf16.h>

typedef unsigned short u16;
typedef __attribute__((ext_vector_type(8))) short bf16x8;
typedef __attribute__((ext_vector_type(4))) float f32x4;

#define MFMA16(a, b, c) __builtin_amdgcn_mfma_f32_16x16x32_bf16(a, b, c, 0, 0, 0)

__device__ __forceinline__ u16 f2b(float f) {
  union { float f; unsigned u; } x; x.f = f;
  return (u16)((x.u + 0x7fffu + ((x.u >> 16) & 1u)) >> 16);
}

__device__ __forceinline__ void gload_lds16(const void* g, void* l) {
  __builtin_amdgcn_global_load_lds(
      (const __attribute__((address_space(1))) void*)g,
      (__attribute__((address_space(3))) void*)l, 16, 0, 0);
}

// linear frag-block stage: NCH chunks of 512 u16 (64 lanes x 16B), src contiguous
template <int NCH>
__device__ __forceinline__ void stage_frags(const u16* __restrict__ src,
                                            u16* dst, int wave, int lane) {
#pragma unroll
  for (int it = 0; it < NCH / 4; ++it) {
    int chunk = it * 4 + wave;
    gload_lds16(src + ((size_t)chunk * 64 + lane) * 8, dst + chunk * 512);
  }
}

// 8-wave combined stage of two 12-frag buffers (3 chunk-loads per wave)
__device__ __forceinline__ void stage12x2_512(const u16* __restrict__ s1,
                                              u16* d1,
                                              const u16* __restrict__ s2,
                                              u16* d2, int wave, int lane) {
#pragma unroll
  for (int it = 0; it < 3; ++it) {
    int id = it * 8 + wave;
    if (id < 12)
      gload_lds16(s1 + ((size_t)id * 64 + lane) * 8, d1 + id * 512);
    else
      gload_lds16(s2 + ((size_t)(id - 12) * 64 + lane) * 8,
                  d2 + (id - 12) * 512);
  }
}

// stage 64 rows x 192 cols bf16 -> LDS, chunk XOR-swizzled by row&7 (proj A).
__device__ __forceinline__ void stage_64x192(const u16* __restrict__ src,
                                             int stride, u16* dst, int wave,
                                             int lane) {
#pragma unroll
  for (int it = 0; it < 6; ++it) {
    int id = (it * 4 + wave) * 64 + lane;
    int row = id / 24, ph = id - row * 24;
    int lch = (ph & 24) | ((ph ^ (row & 7)) & 7);
    gload_lds16(src + (size_t)row * stride + lch * 8,
                dst + (it * 4 + wave) * 512);
  }
}

// ---------------- weight fp32 -> bf16 MFMA-fragment order ------------------
__global__ __launch_bounds__(256) void pack_kernel(const float* __restrict__ W,
                                                   u16* __restrict__ F, int NT,
                                                   int KS, int K, int kmajor) {
  int f = blockIdx.x * 256 + threadIdx.x;
  if (f >= NT * KS * 64) return;
  int l = f & 63, rest = f >> 6;
  int ks, ct;
  if (kmajor) { ct = rest % NT; ks = rest / NT; }
  else        { ks = rest % KS; ct = rest / KS; }
  int row = ct * 16 + (l & 15);
  int col = ks * 32 + (l >> 4) * 8;
  const float* s = W + (size_t)row * K + col;
  u16* d = F + (size_t)f * 8;
#pragma unroll
  for (int i = 0; i < 8; ++i) d[i] = f2b(s[i]);
}

// fc2 pack with pi-permuted k within each 32-h chunk (matches lane-local pf):
// pi(g,i) = 4g+i (i<4), 16+4g+(i-4) (i>=4). frag id = hs*12 + ct.
__global__ __launch_bounds__(256) void pack2_kernel(const float* __restrict__ W,
                                                    u16* __restrict__ F) {
  int f = blockIdx.x * 256 + threadIdx.x;
  if (f >= 24 * 12 * 64) return;
  int l = f & 63, rest = f >> 6;
  int ct = rest % 12, hs = rest / 12;
  int row = ct * 16 + (l & 15);
  int g = l >> 4;
  u16* d = F + (size_t)f * 8;
#pragma unroll
  for (int i = 0; i < 8; ++i) {
    int h = hs * 32 + (i < 4 ? 4 * g + i : 16 + 4 * g + (i - 4));
    d[i] = f2b(W[(size_t)row * 768 + h]);
  }
}

// ---------------- fused LN1 + shift/window + QKV + attention (r14) ---------
__global__ __launch_bounds__(256, 3) void attn_win(
    const float* __restrict__ x, const float* __restrict__ n1w,
    const float* __restrict__ n1b, const u16* __restrict__ qkvwf,
    const float* __restrict__ qkvb_, const float* __restrict__ rpb,
    const float* __restrict__ amask, u16* __restrict__ aout, int win0) {
  __shared__ __align__(16) u16 lds[25088];  // 50,176 B
  u16* wbuf = lds;                // 36 frags (18432 u16); sA overlays
  u16* sA   = lds;                // 64x192 swizzled (12288 u16)
  u16* klds = lds + 18432;        // [64 tok][40] u16 (16B frag words)
  u16* vlds = lds + 21000;        // [32 d][68] u16
  int tid = threadIdx.x, wave = tid >> 6, lane = tid & 63;
  int g = lane >> 4, c = lane & 15, wr = wave * 16;
  int blk = blockIdx.x;
  int wing = win0 + blk;
  int wi = wing & 63;
  // --- LN1 -> sA (rows 49..63 clamp to token 48; masked later) ---
  {
    float vals[12][4];
    int srcrow[4];
#pragma unroll
    for (int reg = 0; reg < 4; ++reg) {
      int n = wr + 4 * g + reg;
      if (n > 48) n = 48;
      int bb = wing >> 6, wloc = wing & 63, wh = wloc >> 3, ww = wloc & 7;
      int rr = n / 7, cc = n - rr * 7;
      int hs = wh * 7 + rr + 3; if (hs >= 56) hs -= 56;
      int wsr = ww * 7 + cc + 3; if (wsr >= 56) wsr -= 56;
      srcrow[reg] = bb * 3136 + hs * 56 + wsr;
    }
#pragma unroll
    for (int nt = 0; nt < 12; ++nt)
#pragma unroll
      for (int reg = 0; reg < 4; ++reg)
        vals[nt][reg] = x[(size_t)srcrow[reg] * 192 + nt * 16 + c];
#pragma unroll
    for (int reg = 0; reg < 4; ++reg) {
      float s = 0.f;
#pragma unroll
      for (int nt = 0; nt < 12; ++nt) s += vals[nt][reg];
      s += __shfl_xor(s, 1, 64); s += __shfl_xor(s, 2, 64);
      s += __shfl_xor(s, 4, 64); s += __shfl_xor(s, 8, 64);
      float m = s * (1.f / 192.f), q = 0.f;
#pragma unroll
      for (int nt = 0; nt < 12; ++nt) { float d = vals[nt][reg] - m; q += d * d; }
      q += __shfl_xor(q, 1, 64); q += __shfl_xor(q, 2, 64);
      q += __shfl_xor(q, 4, 64); q += __shfl_xor(q, 8, 64);
      float rs = rsqrtf(q * (1.f / 192.f) + 1e-5f);
#pragma unroll
      for (int nt = 0; nt < 12; ++nt) vals[nt][reg] = (vals[nt][reg] - m) * rs;
    }
#pragma unroll
    for (int nt = 0; nt < 12; ++nt) {
      float wv = n1w[nt * 16 + c], bv = n1b[nt * 16 + c];
#pragma unroll
      for (int reg = 0; reg < 4; ++reg) {
        int r = wr + 4 * g + reg;
        int ch = nt * 2 + (c >> 3);
        int ph = (ch & 24) | ((ch ^ (r & 7)) & 7);
        sA[r * 192 + ph * 8 + (c & 7)] = f2b(vals[nt][reg] * wv + bv);
      }
    }
  }
  __syncthreads();  // sA visible
  bf16x8 afr[6];
  {
    int ar = wr + c;
#pragma unroll
    for (int ks = 0; ks < 6; ++ks) {
      int ch = ks * 4 + g;
      int ph = (ch & 24) | ((ch ^ (ar & 7)) & 7);
      afr[ks] = *(const bf16x8*)(sA + ar * 192 + ph * 8);
    }
  }
  __syncthreads();  // sA dead everywhere -> wbuf region usable
#pragma unroll
  for (int s = 0; s < 3; ++s)
    stage_frags<12>(qkvwf + (size_t)((s * 12 + 0) * 6) * 512, wbuf + s * 6144,
                    wave, lane);
  int nq = wr + c;
  int nb = nq > 48 ? 48 : nq;
  int ridx[16];
  float pm[16];
  {
    int i1 = nb / 7, j1 = nb - i1 * 7;
#pragma unroll
    for (int kt = 0; kt < 4; ++kt)
#pragma unroll
      for (int reg = 0; reg < 4; ++reg) {
        int m = kt * 16 + 4 * g + reg;
        int idx = kt * 4 + reg;
        if (m < 49) {
          int i2 = m / 7, j2 = m - i2 * 7;
          ridx[idx] = ((i1 - i2 + 6) * 13 + (j1 - j2 + 6)) * 6;
          pm[idx] = amask[(size_t)wi * 2401 + nb * 49 + m];
        } else {
          ridx[idx] = 0;
          pm[idx] = -1e30f;
        }
      }
  }
  __syncthreads();  // W[0] staged
  for (int h = 0; h < 6; ++h) {
    f32x4 qa[2], ka[2], va[2];
#pragma unroll
    for (int s = 0; s < 3; ++s)
#pragma unroll
      for (int t = 0; t < 2; ++t) {
        f32x4 acc = {0.f, 0.f, 0.f, 0.f};
#pragma unroll
        for (int ks = 0; ks < 6; ++ks) {
          bf16x8 wf = *(const bf16x8*)(wbuf + (s * 12 + t * 6 + ks) * 512 +
                                       lane * 8);
          acc = MFMA16(wf, afr[ks], acc);
        }
        float4 b4 = *(const float4*)(qkvb_ + s * 192 + h * 32 + t * 16 + 4 * g);
#pragma unroll
        for (int reg = 0; reg < 4; ++reg) acc[reg] += ((const float*)&b4)[reg];
        if (s == 0) qa[t] = acc;
        else if (s == 1) ka[t] = acc;
        else va[t] = acc;
      }
    union { u16 hh[8]; bf16x8 v; } qf, kf;
#pragma unroll
    for (int reg = 0; reg < 4; ++reg) {
      qf.hh[reg] = f2b(qa[0][reg]);
      qf.hh[reg + 4] = f2b(qa[1][reg]);
      kf.hh[reg] = f2b(ka[0][reg]);
      kf.hh[reg + 4] = f2b(ka[1][reg]);
    }
    *(bf16x8*)(klds + nq * 40 + g * 8) = kf.v;
#pragma unroll
    for (int t = 0; t < 2; ++t)
#pragma unroll
      for (int reg = 0; reg < 4; ++reg)
        vlds[(t * 16 + 4 * g + reg) * 68 + nq] = f2b(va[t][reg]);
    __syncthreads();  // k/v visible; wbuf reads done
    if (h < 5) {
#pragma unroll
      for (int s = 0; s < 3; ++s)
        stage_frags<12>(qkvwf + (size_t)((s * 12 + (h + 1) * 2) * 6) * 512,
                        wbuf + s * 6144, wave, lane);
    }
    float sv[16];
#pragma unroll
    for (int kt = 0; kt < 4; ++kt) {
      bf16x8 kw = *(const bf16x8*)(klds + (kt * 16 + c) * 40 + g * 8);
      f32x4 z = {0.f, 0.f, 0.f, 0.f};
      f32x4 sacc = MFMA16(kw, qf.v, z);
#pragma unroll
      for (int reg = 0; reg < 4; ++reg) sv[kt * 4 + reg] = sacc[reg];
    }
    const float scale = 0.17677669529663687f;
    float mx = -1e30f;
#pragma unroll
    for (int i = 0; i < 16; ++i) {
      sv[i] = sv[i] * scale + rpb[ridx[i] + h] + pm[i];
      mx = fmaxf(mx, sv[i]);
    }
    mx = fmaxf(mx, __shfl_xor(mx, 16, 64));
    mx = fmaxf(mx, __shfl_xor(mx, 32, 64));
    float se = 0.f;
#pragma unroll
    for (int i = 0; i < 16; ++i) {
      sv[i] = __expf(sv[i] - mx);
      se += sv[i];
    }
    se += __shfl_xor(se, 16, 64);
    se += __shfl_xor(se, 32, 64);
    float inv = 1.0f / se;
    union { u16 hh[8]; bf16x8 v; } pu0, pu1;
#pragma unroll
    for (int reg = 0; reg < 4; ++reg) {
      pu0.hh[reg] = f2b(sv[0 * 4 + reg] * inv);
      pu0.hh[reg + 4] = f2b(sv[1 * 4 + reg] * inv);
      pu1.hh[reg] = f2b(sv[2 * 4 + reg] * inv);
      pu1.hh[reg + 4] = f2b(sv[3 * 4 + reg] * inv);
    }
    f32x4 oacc[2] = {{0, 0, 0, 0}, {0, 0, 0, 0}};
#pragma unroll
    for (int nt = 0; nt < 2; ++nt)
#pragma unroll
      for (int mblk = 0; mblk < 2; ++mblk) {
        const u16* vp = vlds + (nt * 16 + c) * 68 + mblk * 32 + 4 * g;
        union { u16 hh[8]; bf16x8 v; } vt;
        *(short4*)(vt.hh) = *(const short4*)(vp);
        *(short4*)(vt.hh + 4) = *(const short4*)(vp + 16);
        oacc[nt] = MFMA16(vt.v, mblk ? pu1.v : pu0.v, oacc[nt]);
      }
    if (nq < 49) {
      u16* op = aout + ((size_t)blk * 49 + nq) * 192 + h * 32;
#pragma unroll
      for (int nt = 0; nt < 2; ++nt) {
        ushort4 st;
        st.x = f2b(oacc[nt][0]);
        st.y = f2b(oacc[nt][1]);
        st.z = f2b(oacc[nt][2]);
        st.w = f2b(oacc[nt][3]);
        *(ushort4*)(op + nt * 16 + 4 * g) = st;
      }
    }
    __syncthreads();
  }
}

// ---------------- fused proj + window reverse + unshift + residual ---------
__global__ __launch_bounds__(256, 3) void proj_fused(
    const u16* __restrict__ aout, const u16* __restrict__ wf,
    const float* __restrict__ pb, const float* __restrict__ x,
    float* __restrict__ out, int tok0) {
  __shared__ __align__(16) u16 lds[24576];  // 48 KB
  u16* sA = lds;
  u16* b0 = lds;
  u16* b1 = lds + 12288;
  int tid = threadIdx.x, wave = tid >> 6, lane = tid & 63;
  int g = lane >> 4, c = lane & 15;
  int m0 = blockIdx.x * 64;
  stage_64x192(aout + (size_t)m0 * 192, 192, sA, wave, lane);
  asm volatile("s_waitcnt vmcnt(0)" ::: "memory");
  __syncthreads();
  int mw = wave >> 1, nw = wave & 1;
  bf16x8 afr[2][6];
#pragma unroll
  for (int rt = 0; rt < 2; ++rt) {
    int ar = mw * 32 + rt * 16 + c;
#pragma unroll
    for (int ks = 0; ks < 6; ++ks) {
      int ch = ks * 4 + g;
      int ph = (ch & 24) | ((ch ^ (ar & 7)) & 7);
      afr[rt][ks] = *(const bf16x8*)(sA + ar * 192 + ph * 8);
    }
  }
  size_t trow[2][4];
#pragma unroll
  for (int rt = 0; rt < 2; ++rt)
#pragma unroll
    for (int reg = 0; reg < 4; ++reg) {
      int rg = tok0 + m0 + mw * 32 + rt * 16 + 4 * g + reg;
      int win = rg / 49, n = rg - win * 49;
      int b_ = win >> 6, wi = win & 63;
      int wh = wi >> 3, ww = wi & 7;
      int rr = n / 7, cc = n - rr * 7;
      int hd_ = wh * 7 + rr + 3; if (hd_ >= 56) hd_ -= 56;
      int wd = ww * 7 + cc + 3; if (wd >= 56) wd -= 56;
      trow[rt][reg] = (size_t)b_ * 3136 + hd_ * 56 + wd;
    }
  __syncthreads();  // afr reads done -> sA region (b0) reusable
  stage_frags<24>(wf, b0, wave, lane);
  __syncthreads();  // b0 staged
  for (int j = 0; j < 3; ++j) {
    const u16* cb = (j & 1) ? b1 : b0;
    if (j < 2)
      stage_frags<24>(wf + (size_t)(j + 1) * 24 * 512, (j & 1) ? b0 : b1, wave,
                      lane);
    f32x4 S[2][2] = {{{0,0,0,0},{0,0,0,0}},{{0,0,0,0},{0,0,0,0}}};
#pragma unroll
    for (int nt = 0; nt < 2; ++nt)
#pragma unroll
      for (int ks = 0; ks < 6; ++ks) {
        bf16x8 bf = *(const bf16x8*)(cb + ((nw * 2 + nt) * 6 + ks) * 512 + lane * 8);
        S[0][nt] = MFMA16(afr[0][ks], bf, S[0][nt]);
        S[1][nt] = MFMA16(afr[1][ks], bf, S[1][nt]);
      }
#pragma unroll
    for (int nt = 0; nt < 2; ++nt) {
      int jc = j * 64 + nw * 32 + nt * 16 + c;
      float bv = pb[jc];
#pragma unroll
      for (int rt = 0; rt < 2; ++rt)
#pragma unroll
        for (int reg = 0; reg < 4; ++reg) {
          size_t o = trow[rt][reg] * 192 + jc;
          out[o] = x[o] + S[rt][nt][reg] + bv;
        }
    }
    __syncthreads();
  }
}

// ---------------- fused LN2 + fc1 + GELU + fc2 + residual ------------------
// r10 structure, 512 threads / 8 waves, M=128: weight LDS shared by 2x waves.
__global__ __launch_bounds__(512, 2) void mlp_fused(
    const float* __restrict__ n2w, const float* __restrict__ n2b,
    const u16* __restrict__ w1f, const float* __restrict__ b1,
    const u16* __restrict__ w2f, const float* __restrict__ b2,
    float* __restrict__ out) {
  __shared__ __align__(16) u16 lds[24576];  // 48 KB
  u16* c1a = lds;            // 12 frags (6144 u16) fc1 buf0
  u16* c1b = lds + 6144;
  u16* c2a = lds + 12288;    // fc2 buf0
  u16* c2b = lds + 18432;
  u16* sA  = lds;            // 128x192 overlay of all four buffers (48 KB)
  int tid = threadIdx.x, wave = tid >> 6, lane = tid & 63;
  int g = lane >> 4, c = lane & 15, wr = wave * 16;
  int m0 = blockIdx.x * 128;
  // --- LN2: each of 8 waves owns 16 rows -> sA swizzled ---
  {
    float v[12][4];
    int rr[4];
#pragma unroll
    for (int reg = 0; reg < 4; ++reg) rr[reg] = m0 + wr + 4 * g + reg;
#pragma unroll
    for (int nt = 0; nt < 12; ++nt)
#pragma unroll
      for (int reg = 0; reg < 4; ++reg)
        v[nt][reg] = out[(size_t)rr[reg] * 192 + nt * 16 + c];
#pragma unroll
    for (int reg = 0; reg < 4; ++reg) {
      float s = 0.f;
#pragma unroll
      for (int nt = 0; nt < 12; ++nt) s += v[nt][reg];
      s += __shfl_xor(s, 1, 64); s += __shfl_xor(s, 2, 64);
      s += __shfl_xor(s, 4, 64); s += __shfl_xor(s, 8, 64);
      float m = s * (1.f / 192.f), q = 0.f;
#pragma unroll
      for (int nt = 0; nt < 12; ++nt) { float d = v[nt][reg] - m; q += d * d; }
      q += __shfl_xor(q, 1, 64); q += __shfl_xor(q, 2, 64);
      q += __shfl_xor(q, 4, 64); q += __shfl_xor(q, 8, 64);
      float rs = rsqrtf(q * (1.f / 192.f) + 1e-5f);
#pragma unroll
      for (int nt = 0; nt < 12; ++nt) v[nt][reg] = (v[nt][reg] - m) * rs;
    }
#pragma unroll
    for (int nt = 0; nt < 12; ++nt) {
      float wv = n2w[nt * 16 + c], bv = n2b[nt * 16 + c];
#pragma unroll
      for (int reg = 0; reg < 4; ++reg) {
        int r = wr + 4 * g + reg;
        int ch = nt * 2 + (c >> 3);
        int ph = (ch & 24) | ((ch ^ (r & 7)) & 7);
        sA[r * 192 + ph * 8 + (c & 7)] = f2b(v[nt][reg] * wv + bv);
      }
    }
  }
  __syncthreads();  // sA visible
  bf16x8 afr[6];
  {
    int ar = wr + c;   // 0..127
#pragma unroll
    for (int ks = 0; ks < 6; ++ks) {
      int ch = ks * 4 + g;
      int ph = (ch & 24) | ((ch ^ (ar & 7)) & 7);
      afr[ks] = *(const bf16x8*)(sA + ar * 192 + ph * 8);
    }
  }
  __syncthreads();  // all afr reads done -> weight buffers reusable
  stage12x2_512(w1f, c1a, w2f, c2a, wave, lane);
  f32x4 o[12];
#pragma unroll
  for (int i = 0; i < 12; ++i) o[i] = (f32x4){0.f, 0.f, 0.f, 0.f};
  __syncthreads();  // prologue stage drained
  for (int j = 0; j < 24; ++j) {
    int cur = j & 1;
    const u16* r1 = cur ? c1b : c1a;
    const u16* r2 = cur ? c2b : c2a;
    if (j < 23)
      stage12x2_512(w1f + (size_t)(j + 1) * 6144, cur ? c1a : c1b,
                    w2f + (size_t)(j + 1) * 6144, cur ? c2a : c2b, wave, lane);
    // ---- swapped fc1: S1[ht] = W1_frag x afr -> lane holds P^T[h][m=wr+c] ----
    f32x4 S1[2] = {{0,0,0,0},{0,0,0,0}};
#pragma unroll
    for (int ks = 0; ks < 6; ++ks) {
      bf16x8 w0 = *(const bf16x8*)(r1 + (0 * 6 + ks) * 512 + lane * 8);
      bf16x8 w1v = *(const bf16x8*)(r1 + (1 * 6 + ks) * 512 + lane * 8);
      S1[0] = MFMA16(w0, afr[ks], S1[0]);
      S1[1] = MFMA16(w1v, afr[ks], S1[1]);
    }
    // ---- GELU + lane-local bf16 pack: pf slot (g,i) = h pi(g,i) ----
    union { u16 h[8]; bf16x8 v; } pu;
    float4 bv0 = *(const float4*)(b1 + j * 32 + 4 * g);
    float4 bv1 = *(const float4*)(b1 + j * 32 + 16 + 4 * g);
#pragma unroll
    for (int r = 0; r < 4; ++r) {
      float v0 = S1[0][r] + ((const float*)&bv0)[r];
      float u20 = v0 * (1.5957691216f + 0.0713548163f * v0 * v0);
      pu.h[r] = f2b(v0 / (1.f + __expf(-u20)));
      float v1 = S1[1][r] + ((const float*)&bv1)[r];
      float u21 = v1 * (1.5957691216f + 0.0713548163f * v1 * v1);
      pu.h[r + 4] = f2b(v1 / (1.f + __expf(-u21)));
    }
    // ---- swapped PV: o[ct] += W2_frag(pi-packed) x pf ----
#pragma unroll
    for (int ct = 0; ct < 12; ++ct) {
      bf16x8 wf2 = *(const bf16x8*)(r2 + ct * 512 + lane * 8);
      o[ct] = MFMA16(wf2, pu.v, o[ct]);
    }
    __syncthreads();  // r1/r2 reads done; stage(j+1) drained
  }
  // epilogue: lane holds O^T[cout=ct*16+4g+r][m=wr+c]; float4 residual RMW
  float* rowp = out + (size_t)(m0 + wr + c) * 192;
#pragma unroll
  for (int ct = 0; ct < 12; ++ct) {
    float4* p = (float4*)(rowp + ct * 16 + 4 * g);
    float4 cu = *p;
    float4 b4 = *(const float4*)(b2 + ct * 16 + 4 * g);
    cu.x += o[ct][0] + b4.x;
    cu.y += o[ct][1] + b4.y;
    cu.z += o[ct][2] + b4.z;
    cu.w += o[ct][3] + b4.w;
    *p = cu;
  }
}

extern "C" void kernel_launch(void* const* d_in, const int* in_sizes, int n_in,
                              void* d_out, int out_size, void* d_ws, size_t ws_size,
                              hipStream_t stream) {
  (void)in_sizes; (void)n_in; (void)out_size;
  const float* x     = (const float*)d_in[0];
  const float* amask = (const float*)d_in[1];
  const float* n1w   = (const float*)d_in[2];
  const float* n1b   = (const float*)d_in[3];
  const float* qkvw  = (const float*)d_in[4];
  const float* qkvb  = (const float*)d_in[5];
  const float* rpb   = (const float*)d_in[6];
  const float* projw = (const float*)d_in[7];
  const float* projb = (const float*)d_in[8];
  const float* n2w   = (const float*)d_in[9];
  const float* n2b   = (const float*)d_in[10];
  const float* fc1w  = (const float*)d_in[11];
  const float* fc1b  = (const float*)d_in[12];
  const float* fc2w  = (const float*)d_in[13];
  const float* fc2b  = (const float*)d_in[14];
  float* out = (float*)d_out;
  char* ws = (char*)d_ws;

  u16* qkvwf = (u16*)(ws);                               // ct-major 36x6
  u16* projwf = (u16*)(ws + 221184);                     // ct-major 12x6
  u16* fc1wf = (u16*)(ws + 221184 + 73728);              // ct-major 48x6
  u16* fc2wf = (u16*)(ws + 221184 + 73728 + 294912);     // pi-packed hs-major 24x12
  char* arena = ws + (1 << 20);
  size_t arena_sz = ws_size > (1 << 20) ? ws_size - (1 << 20) : 0;

  pack_kernel<<<(36 * 6 * 64 + 255) / 256, 256, 0, stream>>>(qkvw, qkvwf, 36, 6, 192, 0);
  pack_kernel<<<(12 * 6 * 64 + 255) / 256, 256, 0, stream>>>(projw, projwf, 12, 6, 192, 0);
  pack_kernel<<<(48 * 6 * 64 + 255) / 256, 256, 0, stream>>>(fc1w, fc1wf, 48, 6, 192, 0);
  pack2_kernel<<<(24 * 12 * 64 + 255) / 256, 256, 0, stream>>>(fc2w, fc2wf);

  // ---- attention path: fused per-window kernel + proj (aout only in ws) ----
  int NCA = 1;
  while (NCA < 16 && (size_t)(2048 / NCA) * 49 * 192 * 2 > arena_sz) NCA <<= 1;
  int Wc = 2048 / NCA;
  for (int cch = 0; cch < NCA; ++cch) {
    int win0 = cch * Wc;
    int tok0 = win0 * 49;
    u16* aout_c = (u16*)arena;
    int rows = Wc * 49;
    attn_win<<<Wc, 256, 0, stream>>>(x, n1w, n1b, qkvwf, qkvb, rpb, amask,
                                     aout_c, win0);
    proj_fused<<<rows / 64, 256, 0, stream>>>(aout_c, projwf, projb, x, out,
                                              tok0);
  }

  // ---- fused MLP: 512 threads / 8 waves share the weight LDS ----
  mlp_fused<<<784, 512, 0, stream>>>(n2w, n2b, fc1wf, fc1b, fc2wf, fc2b,
                                     out);
}

// Round 16
// 254.511 us; speedup vs baseline: 1.1205x; 1.1205x over previous
//
#include <hip/hip_runtime.h>
#include <hip/hip_bf16.h>

typedef unsigned short u16;
typedef __attribute__((ext_vector_type(8))) short bf16x8;
typedef __attribute__((ext_vector_type(4))) float f32x4;

#define MFMA16(a, b, c) __builtin_amdgcn_mfma_f32_16x16x32_bf16(a, b, c, 0, 0, 0)

__device__ __forceinline__ u16 f2b(float f) {
  union { float f; unsigned u; } x; x.f = f;
  return (u16)((x.u + 0x7fffu + ((x.u >> 16) & 1u)) >> 16);
}

__device__ __forceinline__ void gload_lds16(const void* g, void* l) {
  __builtin_amdgcn_global_load_lds(
      (const __attribute__((address_space(1))) void*)g,
      (__attribute__((address_space(3))) void*)l, 16, 0, 0);
}

// linear frag-block stage: NCH chunks of 512 u16 (64 lanes x 16B), src contiguous
template <int NCH>
__device__ __forceinline__ void stage_frags(const u16* __restrict__ src,
                                            u16* dst, int wave, int lane) {
#pragma unroll
  for (int it = 0; it < NCH / 4; ++it) {
    int chunk = it * 4 + wave;
    gload_lds16(src + ((size_t)chunk * 64 + lane) * 8, dst + chunk * 512);
  }
}

// ---------------- weight fp32 -> bf16 MFMA-fragment order ------------------
__global__ __launch_bounds__(256) void pack_kernel(const float* __restrict__ W,
                                                   u16* __restrict__ F, int NT,
                                                   int KS, int K, int kmajor) {
  int f = blockIdx.x * 256 + threadIdx.x;
  if (f >= NT * KS * 64) return;
  int l = f & 63, rest = f >> 6;
  int ks, ct;
  if (kmajor) { ct = rest % NT; ks = rest / NT; }
  else        { ks = rest % KS; ct = rest / KS; }
  int row = ct * 16 + (l & 15);
  int col = ks * 32 + (l >> 4) * 8;
  const float* s = W + (size_t)row * K + col;
  u16* d = F + (size_t)f * 8;
#pragma unroll
  for (int i = 0; i < 8; ++i) d[i] = f2b(s[i]);
}

// fc2 pack with pi-permuted k within each 32-h chunk (matches lane-local pf):
// pi(g,i) = 4g+i (i<4), 16+4g+(i-4) (i>=4). frag id = hs*12 + ct.
__global__ __launch_bounds__(256) void pack2_kernel(const float* __restrict__ W,
                                                    u16* __restrict__ F) {
  int f = blockIdx.x * 256 + threadIdx.x;
  if (f >= 24 * 12 * 64) return;
  int l = f & 63, rest = f >> 6;
  int ct = rest % 12, hs = rest / 12;
  int row = ct * 16 + (l & 15);
  int g = l >> 4;
  u16* d = F + (size_t)f * 8;
#pragma unroll
  for (int i = 0; i < 8; ++i) {
    int h = hs * 32 + (i < 4 ? 4 * g + i : 16 + 4 * g + (i - 4));
    d[i] = f2b(W[(size_t)row * 768 + h]);
  }
}

// proj pack, pi-permuted k, half-major: frag id = half*36 + ks*6 + ctl.
// row (out col) = (half*6+ctl)*16 + (l&15); k = ks*32 + pi(g,i); K=192.
__global__ __launch_bounds__(256) void pack_proj_pi(const float* __restrict__ W,
                                                    u16* __restrict__ F) {
  int f = blockIdx.x * 256 + threadIdx.x;
  if (f >= 72 * 64) return;
  int l = f & 63, rest = f >> 6;
  int half = rest / 36, r2 = rest - half * 36;
  int ks = r2 / 6, ctl = r2 - ks * 6;
  int row = (half * 6 + ctl) * 16 + (l & 15);
  int g = l >> 4;
  u16* d = F + (size_t)f * 8;
#pragma unroll
  for (int i = 0; i < 8; ++i) {
    int k = ks * 32 + (i < 4 ? 4 * g + i : 16 + 4 * g + (i - 4));
    d[i] = f2b(W[(size_t)row * 192 + k]);
  }
}

// ------- fused LN1 + shift/window + QKV + attention + proj + residual ------
__global__ __launch_bounds__(256, 3) void attn_win(
    const float* __restrict__ x, const float* __restrict__ n1w,
    const float* __restrict__ n1b, const u16* __restrict__ qkvwf,
    const float* __restrict__ qkvb_, const float* __restrict__ rpb,
    const float* __restrict__ amask, const u16* __restrict__ pwf,
    const float* __restrict__ pb, float* __restrict__ out) {
  __shared__ __align__(16) u16 lds[25088];  // 50,176 B
  u16* wbuf = lds;                // 36 frags (18432 u16); sA / proj overlay
  u16* sA   = lds;                // 64x192 swizzled (12288 u16)
  u16* klds = lds + 18432;        // [64 tok][40] u16 (16B frag words)
  u16* vlds = lds + 21000;        // [32 d][68] u16
  int tid = threadIdx.x, wave = tid >> 6, lane = tid & 63;
  int g = lane >> 4, c = lane & 15, wr = wave * 16;
  int wing = blockIdx.x;          // global window index
  int wi = wing & 63;
  // --- LN1 -> sA (rows 49..63 clamp to token 48; masked later) ---
  {
    float vals[12][4];
    int srcrow[4];
#pragma unroll
    for (int reg = 0; reg < 4; ++reg) {
      int n = wr + 4 * g + reg;
      if (n > 48) n = 48;
      int bb = wing >> 6, wloc = wing & 63, wh = wloc >> 3, ww = wloc & 7;
      int rr = n / 7, cc = n - rr * 7;
      int hs = wh * 7 + rr + 3; if (hs >= 56) hs -= 56;
      int wsr = ww * 7 + cc + 3; if (wsr >= 56) wsr -= 56;
      srcrow[reg] = bb * 3136 + hs * 56 + wsr;
    }
#pragma unroll
    for (int nt = 0; nt < 12; ++nt)
#pragma unroll
      for (int reg = 0; reg < 4; ++reg)
        vals[nt][reg] = x[(size_t)srcrow[reg] * 192 + nt * 16 + c];
#pragma unroll
    for (int reg = 0; reg < 4; ++reg) {
      float s = 0.f;
#pragma unroll
      for (int nt = 0; nt < 12; ++nt) s += vals[nt][reg];
      s += __shfl_xor(s, 1, 64); s += __shfl_xor(s, 2, 64);
      s += __shfl_xor(s, 4, 64); s += __shfl_xor(s, 8, 64);
      float m = s * (1.f / 192.f), q = 0.f;
#pragma unroll
      for (int nt = 0; nt < 12; ++nt) { float d = vals[nt][reg] - m; q += d * d; }
      q += __shfl_xor(q, 1, 64); q += __shfl_xor(q, 2, 64);
      q += __shfl_xor(q, 4, 64); q += __shfl_xor(q, 8, 64);
      float rs = rsqrtf(q * (1.f / 192.f) + 1e-5f);
#pragma unroll
      for (int nt = 0; nt < 12; ++nt) vals[nt][reg] = (vals[nt][reg] - m) * rs;
    }
#pragma unroll
    for (int nt = 0; nt < 12; ++nt) {
      float wv = n1w[nt * 16 + c], bv = n1b[nt * 16 + c];
#pragma unroll
      for (int reg = 0; reg < 4; ++reg) {
        int r = wr + 4 * g + reg;
        int ch = nt * 2 + (c >> 3);
        int ph = (ch & 24) | ((ch ^ (r & 7)) & 7);
        sA[r * 192 + ph * 8 + (c & 7)] = f2b(vals[nt][reg] * wv + bv);
      }
    }
  }
  __syncthreads();  // sA visible
  bf16x8 afr[6];
  {
    int ar = wr + c;
#pragma unroll
    for (int ks = 0; ks < 6; ++ks) {
      int ch = ks * 4 + g;
      int ph = (ch & 24) | ((ch ^ (ar & 7)) & 7);
      afr[ks] = *(const bf16x8*)(sA + ar * 192 + ph * 8);
    }
  }
  __syncthreads();  // sA dead everywhere -> wbuf region usable
#pragma unroll
  for (int s = 0; s < 3; ++s)
    stage_frags<12>(qkvwf + (size_t)((s * 12 + 0) * 6) * 512, wbuf + s * 6144,
                    wave, lane);
  int nq = wr + c;
  int nb = nq > 48 ? 48 : nq;
  int ridx[16];
  float pm[16];
  {
    int i1 = nb / 7, j1 = nb - i1 * 7;
#pragma unroll
    for (int kt = 0; kt < 4; ++kt)
#pragma unroll
      for (int reg = 0; reg < 4; ++reg) {
        int m = kt * 16 + 4 * g + reg;
        int idx = kt * 4 + reg;
        if (m < 49) {
          int i2 = m / 7, j2 = m - i2 * 7;
          ridx[idx] = ((i1 - i2 + 6) * 13 + (j1 - j2 + 6)) * 6;
          pm[idx] = amask[(size_t)wi * 2401 + nb * 49 + m];
        } else {
          ridx[idx] = 0;
          pm[idx] = -1e30f;
        }
      }
  }
  __syncthreads();  // W[0] staged
  bf16x8 ofr[6];    // O row as 6 pi-frags (filled per head)
#pragma unroll
  for (int h = 0; h < 6; ++h) {
    f32x4 qa[2], ka[2], va[2];
#pragma unroll
    for (int s = 0; s < 3; ++s)
#pragma unroll
      for (int t = 0; t < 2; ++t) {
        f32x4 acc = {0.f, 0.f, 0.f, 0.f};
#pragma unroll
        for (int ks = 0; ks < 6; ++ks) {
          bf16x8 wf = *(const bf16x8*)(wbuf + (s * 12 + t * 6 + ks) * 512 +
                                       lane * 8);
          acc = MFMA16(wf, afr[ks], acc);
        }
        float4 b4 = *(const float4*)(qkvb_ + s * 192 + h * 32 + t * 16 + 4 * g);
#pragma unroll
        for (int reg = 0; reg < 4; ++reg) acc[reg] += ((const float*)&b4)[reg];
        if (s == 0) qa[t] = acc;
        else if (s == 1) ka[t] = acc;
        else va[t] = acc;
      }
    union { u16 hh[8]; bf16x8 v; } qf, kf;
#pragma unroll
    for (int reg = 0; reg < 4; ++reg) {
      qf.hh[reg] = f2b(qa[0][reg]);
      qf.hh[reg + 4] = f2b(qa[1][reg]);
      kf.hh[reg] = f2b(ka[0][reg]);
      kf.hh[reg + 4] = f2b(ka[1][reg]);
    }
    *(bf16x8*)(klds + nq * 40 + g * 8) = kf.v;
#pragma unroll
    for (int t = 0; t < 2; ++t)
#pragma unroll
      for (int reg = 0; reg < 4; ++reg)
        vlds[(t * 16 + 4 * g + reg) * 68 + nq] = f2b(va[t][reg]);
    __syncthreads();  // k/v visible; wbuf reads done
    if (h < 5) {
#pragma unroll
      for (int s = 0; s < 3; ++s)
        stage_frags<12>(qkvwf + (size_t)((s * 12 + (h + 1) * 2) * 6) * 512,
                        wbuf + s * 6144, wave, lane);
    }
    float sv[16];
#pragma unroll
    for (int kt = 0; kt < 4; ++kt) {
      bf16x8 kw = *(const bf16x8*)(klds + (kt * 16 + c) * 40 + g * 8);
      f32x4 z = {0.f, 0.f, 0.f, 0.f};
      f32x4 sacc = MFMA16(kw, qf.v, z);
#pragma unroll
      for (int reg = 0; reg < 4; ++reg) sv[kt * 4 + reg] = sacc[reg];
    }
    const float scale = 0.17677669529663687f;
    float mx = -1e30f;
#pragma unroll
    for (int i = 0; i < 16; ++i) {
      sv[i] = sv[i] * scale + rpb[ridx[i] + h] + pm[i];
      mx = fmaxf(mx, sv[i]);
    }
    mx = fmaxf(mx, __shfl_xor(mx, 16, 64));
    mx = fmaxf(mx, __shfl_xor(mx, 32, 64));
    float se = 0.f;
#pragma unroll
    for (int i = 0; i < 16; ++i) {
      sv[i] = __expf(sv[i] - mx);
      se += sv[i];
    }
    se += __shfl_xor(se, 16, 64);
    se += __shfl_xor(se, 32, 64);
    float inv = 1.0f / se;
    union { u16 hh[8]; bf16x8 v; } pu0, pu1;
#pragma unroll
    for (int reg = 0; reg < 4; ++reg) {
      pu0.hh[reg] = f2b(sv[0 * 4 + reg] * inv);
      pu0.hh[reg + 4] = f2b(sv[1 * 4 + reg] * inv);
      pu1.hh[reg] = f2b(sv[2 * 4 + reg] * inv);
      pu1.hh[reg + 4] = f2b(sv[3 * 4 + reg] * inv);
    }
    f32x4 oacc[2] = {{0, 0, 0, 0}, {0, 0, 0, 0}};
#pragma unroll
    for (int nt = 0; nt < 2; ++nt)
#pragma unroll
      for (int mblk = 0; mblk < 2; ++mblk) {
        const u16* vp = vlds + (nt * 16 + c) * 68 + mblk * 32 + 4 * g;
        union { u16 hh[8]; bf16x8 v; } vt;
        *(short4*)(vt.hh) = *(const short4*)(vp);
        *(short4*)(vt.hh + 4) = *(const short4*)(vp + 16);
        oacc[nt] = MFMA16(vt.v, mblk ? pu1.v : pu0.v, oacc[nt]);
      }
    // pack O-head into pi-frag (lane-local; d = h*32 + pi(g,i))
    {
      union { u16 hh[8]; bf16x8 v; } of_;
#pragma unroll
      for (int reg = 0; reg < 4; ++reg) {
        of_.hh[reg] = f2b(oacc[0][reg]);
        of_.hh[reg + 4] = f2b(oacc[1][reg]);
      }
      ofr[h] = of_.v;
    }
    __syncthreads();  // klds/vlds reads done; W[h+1] stage drained
  }
  // ---- fused proj: two 36-frag halves; O^T x W + x residual -> out ----
  size_t trow = 0;
  if (nq < 49) {
    int rr = nq / 7, cc2 = nq - rr * 7;
    int wloc = wing & 63, wh = wloc >> 3, ww2 = wloc & 7;
    int hs2 = wh * 7 + rr + 3; if (hs2 >= 56) hs2 -= 56;
    int ws2 = ww2 * 7 + cc2 + 3; if (ws2 >= 56) ws2 -= 56;
    trow = (size_t)(wing >> 6) * 3136 + hs2 * 56 + ws2;
  }
#pragma unroll
  for (int half = 0; half < 2; ++half) {
#pragma unroll
    for (int it = 0; it < 9; ++it) {
      int chunk = it * 4 + wave;
      gload_lds16(pwf + ((size_t)(half * 36 + chunk) * 64 + lane) * 8,
                  lds + chunk * 512);
    }
    asm volatile("s_waitcnt vmcnt(0)" ::: "memory");
    __syncthreads();  // half staged
    f32x4 op6[6];
#pragma unroll
    for (int i = 0; i < 6; ++i) op6[i] = (f32x4){0.f, 0.f, 0.f, 0.f};
#pragma unroll
    for (int ks = 0; ks < 6; ++ks)
#pragma unroll
      for (int ctl = 0; ctl < 6; ++ctl) {
        bf16x8 wf = *(const bf16x8*)(lds + (ks * 6 + ctl) * 512 + lane * 8);
        op6[ctl] = MFMA16(wf, ofr[ks], op6[ctl]);
      }
    if (nq < 49) {
      float* rowp = out + trow * 192 + half * 96;
      const float* xp = x + trow * 192 + half * 96;
#pragma unroll
      for (int ctl = 0; ctl < 6; ++ctl) {
        int colo = ctl * 16 + 4 * g;
        float4 xv = *(const float4*)(xp + colo);
        float4 b4 = *(const float4*)(pb + half * 96 + colo);
        float4 st;
        st.x = xv.x + op6[ctl][0] + b4.x;
        st.y = xv.y + op6[ctl][1] + b4.y;
        st.z = xv.z + op6[ctl][2] + b4.z;
        st.w = xv.w + op6[ctl][3] + b4.w;
        *(float4*)(rowp + colo) = st;
      }
    }
    __syncthreads();  // lds reads done before restage / exit
  }
}

// ---------------- fused LN2 + fc1 + GELU + fc2 + residual (r10 exact) ------
__global__ __launch_bounds__(256, 3) void mlp_fused(
    const float* __restrict__ n2w, const float* __restrict__ n2b,
    const u16* __restrict__ w1f, const float* __restrict__ b1,
    const u16* __restrict__ w2f, const float* __restrict__ b2,
    float* __restrict__ out) {
  __shared__ __align__(16) u16 lds[24576];  // 48 KB
  u16* c1a = lds;            // 12 frags (6144 u16) fc1 buf0
  u16* c1b = lds + 6144;
  u16* c2a = lds + 12288;    // fc2 buf0
  u16* c2b = lds + 18432;
  u16* sA  = lds;            // 64x192 overlay (c1a+c1b), dead after afr loads
  int tid = threadIdx.x, wave = tid >> 6, lane = tid & 63;
  int g = lane >> 4, c = lane & 15, wr = wave * 16;
  int m0 = blockIdx.x * 64;
  // --- LN2: wave owns 16 rows -> sA swizzled ---
  {
    float v[12][4];
    int rr[4];
#pragma unroll
    for (int reg = 0; reg < 4; ++reg) rr[reg] = m0 + wr + 4 * g + reg;
#pragma unroll
    for (int nt = 0; nt < 12; ++nt)
#pragma unroll
      for (int reg = 0; reg < 4; ++reg)
        v[nt][reg] = out[(size_t)rr[reg] * 192 + nt * 16 + c];
#pragma unroll
    for (int reg = 0; reg < 4; ++reg) {
      float s = 0.f;
#pragma unroll
      for (int nt = 0; nt < 12; ++nt) s += v[nt][reg];
      s += __shfl_xor(s, 1, 64); s += __shfl_xor(s, 2, 64);
      s += __shfl_xor(s, 4, 64); s += __shfl_xor(s, 8, 64);
      float m = s * (1.f / 192.f), q = 0.f;
#pragma unroll
      for (int nt = 0; nt < 12; ++nt) { float d = v[nt][reg] - m; q += d * d; }
      q += __shfl_xor(q, 1, 64); q += __shfl_xor(q, 2, 64);
      q += __shfl_xor(q, 4, 64); q += __shfl_xor(q, 8, 64);
      float rs = rsqrtf(q * (1.f / 192.f) + 1e-5f);
#pragma unroll
      for (int nt = 0; nt < 12; ++nt) v[nt][reg] = (v[nt][reg] - m) * rs;
    }
#pragma unroll
    for (int nt = 0; nt < 12; ++nt) {
      float wv = n2w[nt * 16 + c], bv = n2b[nt * 16 + c];
#pragma unroll
      for (int reg = 0; reg < 4; ++reg) {
        int r = wr + 4 * g + reg;
        int ch = nt * 2 + (c >> 3);
        int ph = (ch & 24) | ((ch ^ (r & 7)) & 7);
        sA[r * 192 + ph * 8 + (c & 7)] = f2b(v[nt][reg] * wv + bv);
      }
    }
  }
  __syncthreads();  // sA visible
  bf16x8 afr[6];
  {
    int ar = wr + c;
#pragma unroll
    for (int ks = 0; ks < 6; ++ks) {
      int ch = ks * 4 + g;
      int ph = (ch & 24) | ((ch ^ (ar & 7)) & 7);
      afr[ks] = *(const bf16x8*)(sA + ar * 192 + ph * 8);
    }
  }
  __syncthreads();  // all afr reads done -> sA region (c1a/c1b) reusable
  stage_frags<12>(w1f, c1a, wave, lane);
  stage_frags<12>(w2f, c2a, wave, lane);
  f32x4 o[12];
#pragma unroll
  for (int i = 0; i < 12; ++i) o[i] = (f32x4){0.f, 0.f, 0.f, 0.f};
  __syncthreads();  // prologue stage drained
  for (int j = 0; j < 24; ++j) {
    int cur = j & 1;
    const u16* r1 = cur ? c1b : c1a;
    const u16* r2 = cur ? c2b : c2a;
    if (j < 23) {
      stage_frags<12>(w1f + (size_t)(j + 1) * 6144, cur ? c1a : c1b, wave, lane);
      stage_frags<12>(w2f + (size_t)(j + 1) * 6144, cur ? c2a : c2b, wave, lane);
    }
    // ---- swapped fc1: S1[ht] = W1_frag x afr -> lane holds P^T[h][m=wr+c] ----
    f32x4 S1[2] = {{0,0,0,0},{0,0,0,0}};
#pragma unroll
    for (int ks = 0; ks < 6; ++ks) {
      bf16x8 w0 = *(const bf16x8*)(r1 + (0 * 6 + ks) * 512 + lane * 8);
      bf16x8 w1v = *(const bf16x8*)(r1 + (1 * 6 + ks) * 512 + lane * 8);
      S1[0] = MFMA16(w0, afr[ks], S1[0]);
      S1[1] = MFMA16(w1v, afr[ks], S1[1]);
    }
    // ---- GELU + lane-local bf16 pack: pf slot (g,i) = h pi(g,i) ----
    union { u16 h[8]; bf16x8 v; } pu;
    float4 bv0 = *(const float4*)(b1 + j * 32 + 4 * g);
    float4 bv1 = *(const float4*)(b1 + j * 32 + 16 + 4 * g);
#pragma unroll
    for (int r = 0; r < 4; ++r) {
      float v0 = S1[0][r] + ((const float*)&bv0)[r];
      float u20 = v0 * (1.5957691216f + 0.0713548163f * v0 * v0);
      pu.h[r] = f2b(v0 / (1.f + __expf(-u20)));
      float v1 = S1[1][r] + ((const float*)&bv1)[r];
      float u21 = v1 * (1.5957691216f + 0.0713548163f * v1 * v1);
      pu.h[r + 4] = f2b(v1 / (1.f + __expf(-u21)));
    }
    // ---- swapped PV: o[ct] += W2_frag(pi-packed) x pf ----
#pragma unroll
    for (int ct = 0; ct < 12; ++ct) {
      bf16x8 wf2 = *(const bf16x8*)(r2 + ct * 512 + lane * 8);
      o[ct] = MFMA16(wf2, pu.v, o[ct]);
    }
    __syncthreads();  // r1/r2 reads done; stage(j+1) drained
  }
  // epilogue: lane holds O^T[cout=ct*16+4g+r][m=wr+c]; residual RMW + bias
  size_t rowoff = (size_t)(m0 + wr + c) * 192;
#pragma unroll
  for (int ct = 0; ct < 12; ++ct) {
    float4 b4 = *(const float4*)(b2 + ct * 16 + 4 * g);
#pragma unroll
    for (int r = 0; r < 4; ++r) {
      size_t oo = rowoff + ct * 16 + 4 * g + r;
      out[oo] = out[oo] + o[ct][r] + ((const float*)&b4)[r];
    }
  }
}

extern "C" void kernel_launch(void* const* d_in, const int* in_sizes, int n_in,
                              void* d_out, int out_size, void* d_ws, size_t ws_size,
                              hipStream_t stream) {
  (void)in_sizes; (void)n_in; (void)out_size; (void)ws_size;
  const float* x     = (const float*)d_in[0];
  const float* amask = (const float*)d_in[1];
  const float* n1w   = (const float*)d_in[2];
  const float* n1b   = (const float*)d_in[3];
  const float* qkvw  = (const float*)d_in[4];
  const float* qkvb  = (const float*)d_in[5];
  const float* rpb   = (const float*)d_in[6];
  const float* projw = (const float*)d_in[7];
  const float* projb = (const float*)d_in[8];
  const float* n2w   = (const float*)d_in[9];
  const float* n2b   = (const float*)d_in[10];
  const float* fc1w  = (const float*)d_in[11];
  const float* fc1b  = (const float*)d_in[12];
  const float* fc2w  = (const float*)d_in[13];
  const float* fc2b  = (const float*)d_in[14];
  float* out = (float*)d_out;
  char* ws = (char*)d_ws;

  u16* qkvwf = (u16*)(ws);                               // ct-major 36x6
  u16* projwf = (u16*)(ws + 221184);                     // pi half-major 72
  u16* fc1wf = (u16*)(ws + 221184 + 73728);              // ct-major 48x6
  u16* fc2wf = (u16*)(ws + 221184 + 73728 + 294912);     // pi hs-major 24x12

  pack_kernel<<<(36 * 6 * 64 + 255) / 256, 256, 0, stream>>>(qkvw, qkvwf, 36, 6, 192, 0);
  pack_proj_pi<<<(72 * 64 + 255) / 256, 256, 0, stream>>>(projw, projwf);
  pack_kernel<<<(48 * 6 * 64 + 255) / 256, 256, 0, stream>>>(fc1w, fc1wf, 48, 6, 192, 0);
  pack2_kernel<<<(24 * 12 * 64 + 255) / 256, 256, 0, stream>>>(fc2w, fc2wf);

  // ---- attention path: one fused kernel (LN1+qkv+attn+proj+residual) ----
  attn_win<<<2048, 256, 0, stream>>>(x, n1w, n1b, qkvwf, qkvb, rpb, amask,
                                     projwf, projb, out);

  // ---- fused MLP: r10-exact (validated 160 us) ----
  mlp_fused<<<1568, 256, 0, stream>>>(n2w, n2b, fc1wf, fc1b, fc2wf, fc2b,
                                      out);
}